// Round 15
// baseline (120.298 us; speedup 1.0000x reference)
//
#include <hip/hip_runtime.h>
#include <hip/hip_bf16.h>

typedef __attribute__((ext_vector_type(8))) short bf16x8;
typedef __attribute__((ext_vector_type(4))) float f32x4;

#define NH 12
#define HD 64
#define TT 1536
#define CC 768
#define BB 4
#define MM (BB * TT)   // 6144 rows
#define LOG2E 1.44269504088896f
#define SSHIFT 14.4269504089f   // 10*log2e

__device__ __forceinline__ unsigned short f2bf(float f) {
    unsigned int u = __builtin_bit_cast(unsigned int, f);
    return (unsigned short)((u + 0x7FFFu + ((u >> 16) & 1u)) >> 16);  // RNE
}

__device__ __forceinline__ unsigned short nbf(float f) {   // native convert
    __hip_bfloat16 h = __float2bfloat16(f);
    return __builtin_bit_cast(unsigned short, h);
}

// async global->LDS, 16B per lane; lds dest = wave-uniform base + lane*16
__device__ __forceinline__ void gl_lds16(const unsigned short* g, unsigned short* l) {
    __builtin_amdgcn_global_load_lds(
        (const __attribute__((address_space(1))) void*)g,
        (__attribute__((address_space(3))) void*)l,
        16, 0, 0);
}

// single launch: convert x and all 4 weights fp32 -> bf16 (region-decoded)
#define N4W (CC * CC / 4)
#define N4X (MM * CC / 4)
__global__ __launch_bounds__(256) void convert_all(
    const float* __restrict__ x,
    const float* __restrict__ w0, const float* __restrict__ w1,
    const float* __restrict__ w2, const float* __restrict__ w3,
    unsigned short* __restrict__ xo,
    unsigned short* __restrict__ o0, unsigned short* __restrict__ o1,
    unsigned short* __restrict__ o2, unsigned short* __restrict__ o3) {
    int i = blockIdx.x * 256 + threadIdx.x;
    const float* in;
    unsigned short* out;
    int j;
    if (i < N4X) {
        in = x; out = xo; j = i;
    } else {
        int t = i - N4X;
        int which = t / N4W;
        j = t - which * N4W;
        in = which == 0 ? w0 : which == 1 ? w1 : which == 2 ? w2 : w3;
        out = which == 0 ? o0 : which == 1 ? o1 : which == 2 ? o2 : o3;
    }
    float4 v = reinterpret_cast<const float4*>(in)[j];
    ushort4 o = { f2bf(v.x), f2bf(v.y), f2bf(v.z), f2bf(v.w) };
    reinterpret_cast<ushort4*>(out)[j] = o;
}

// Simple single-buffered K-loop (R11-proven), BK=64, 12 rounds.
// Swizzle (rule #21): LDS slot s of row r holds global chunk s ^ (r&7).
#define GEMM_KLOOP(APTR, BPTR)                                                \
    for (int kt = 0; kt < 12; kt++) {                                         \
        const int k0 = kt * 64;                                               \
        __syncthreads();                                                      \
        _Pragma("unroll")                                                     \
        for (int i = 0; i < 4; i++) {                                         \
            gl_lds16(&APTR[(size_t)(m0 + i * 32 + sr) * CC + k0 + sc],        \
                     as0 + (i * 32 + w * 8) * 64);                            \
            gl_lds16(&BPTR[(size_t)(n0 + i * 32 + sr) * CC + k0 + sc],        \
                     bs0 + (i * 32 + w * 8) * 64);                            \
        }                                                                     \
        __syncthreads();                                                      \
        _Pragma("unroll")                                                     \
        for (int s = 0; s < 2; s++) {                                         \
            const int swz = ((s * 4 + fg) ^ (fr & 7)) * 8;                    \
            bf16x8 a[4], b[4];                                                \
            _Pragma("unroll")                                                 \
            for (int mi = 0; mi < 4; mi++)                                    \
                a[mi] = *reinterpret_cast<const bf16x8*>(                     \
                    as0 + (wr * 64 + mi * 16 + fr) * 64 + swz);               \
            _Pragma("unroll")                                                 \
            for (int ni = 0; ni < 4; ni++)                                    \
                b[ni] = *reinterpret_cast<const bf16x8*>(                     \
                    bs0 + (wc * 64 + ni * 16 + fr) * 64 + swz);               \
            _Pragma("unroll")                                                 \
            for (int mi = 0; mi < 4; mi++)                                    \
                _Pragma("unroll")                                             \
                for (int ni = 0; ni < 4; ni++)                                \
                    acc[mi][ni] = __builtin_amdgcn_mfma_f32_16x16x32_bf16(    \
                        a[mi], b[ni], acc[mi][ni], 0, 0, 0);                  \
        }                                                                     \
    }

// ---------------------------------------------------------------------------
// QKV projection GEMM; BK=64 swizzled gl_lds staging; bias folded into C-init.
// q -> [B,H,T,D] scaled 0.125*log2e; k -> [B,H,T,D]; v -> [B,H,D,T]
// ---------------------------------------------------------------------------
__global__ __launch_bounds__(256) void gemm_qkv(
    const unsigned short* __restrict__ xb,
    const unsigned short* __restrict__ wq, const float* __restrict__ bq,
    const unsigned short* __restrict__ wk, const float* __restrict__ bk,
    const unsigned short* __restrict__ wv, const float* __restrict__ bv,
    unsigned short* __restrict__ qo, unsigned short* __restrict__ ko,
    unsigned short* __restrict__ vo) {
    __shared__ unsigned short As[128][64];
    __shared__ unsigned short Bs[128][64];

    const int wg = (blockIdx.x & 7) * 108 + (blockIdx.x >> 3);
    const int z = wg / 288;
    const int rem = wg % 288;
    const int m0 = (rem / 6) * 128;
    const int n0 = (rem % 6) * 128;

    const unsigned short* W = (z == 0) ? wq : (z == 1) ? wk : wv;
    const float* bias = (z == 0) ? bq : (z == 1) ? bk : bv;
    unsigned short* out = (z == 0) ? qo : (z == 1) ? ko : vo;
    const float scale = (z == 0) ? 0.125f * LOG2E : 1.0f;

    const int tid = threadIdx.x;
    const int lane = tid & 63;
    const int w = tid >> 6;
    const int wr = w >> 1, wc = w & 1;
    const int fr = lane & 15, fg = lane >> 4;

    const int sr = tid >> 3;
    const int sc = ((tid & 7) ^ ((tid >> 3) & 7)) * 8;
    unsigned short* as0 = &As[0][0];
    unsigned short* bs0 = &Bs[0][0];

    f32x4 acc[4][4];
#pragma unroll
    for (int ni = 0; ni < 4; ni++) {
        float bv_ = bias[n0 + wc * 64 + ni * 16 + fr];
#pragma unroll
        for (int mi = 0; mi < 4; mi++)
            acc[mi][ni] = (f32x4){bv_, bv_, bv_, bv_};
    }

    GEMM_KLOOP(xb, W)

#pragma unroll
    for (int mi = 0; mi < 4; mi++)
#pragma unroll
        for (int ni = 0; ni < 4; ni++) {
            int n = n0 + wc * 64 + ni * 16 + fr;
            int h = n >> 6, d = n & 63;
            int m_base = m0 + wr * 64 + mi * 16 + fg * 4;
            int b_ = m_base / TT, t0 = m_base % TT;
            if (z == 2) {
                size_t off = ((size_t)(b_ * NH + h) * HD + d) * (size_t)TT + t0;
                ushort4 o = { nbf(acc[mi][ni][0]), nbf(acc[mi][ni][1]),
                              nbf(acc[mi][ni][2]), nbf(acc[mi][ni][3]) };
                *reinterpret_cast<ushort4*>(&out[off]) = o;
            } else {
#pragma unroll
                for (int r = 0; r < 4; r++) {
                    size_t off = ((size_t)(b_ * NH + h) * TT + t0 + r) * (size_t)HD + d;
                    out[off] = nbf(acc[mi][ni][r] * scale);
                }
            }
        }
}

// ---------------------------------------------------------------------------
// Output projection GEMM: same staging; bias in C-init. fp32 out [M,C].
// ---------------------------------------------------------------------------
__global__ __launch_bounds__(256) void gemm_proj(
    const unsigned short* __restrict__ yb,
    const unsigned short* __restrict__ wp, const float* __restrict__ bp,
    float* __restrict__ out) {
    __shared__ unsigned short As[128][64];
    __shared__ unsigned short Bs[128][64];

    const int wg = (blockIdx.x & 7) * 36 + (blockIdx.x >> 3);  // nwg=288
    const int m0 = (wg / 6) * 128;
    const int n0 = (wg % 6) * 128;

    const int tid = threadIdx.x;
    const int lane = tid & 63;
    const int w = tid >> 6;
    const int wr = w >> 1, wc = w & 1;
    const int fr = lane & 15, fg = lane >> 4;

    const int sr = tid >> 3;
    const int sc = ((tid & 7) ^ ((tid >> 3) & 7)) * 8;
    unsigned short* as0 = &As[0][0];
    unsigned short* bs0 = &Bs[0][0];

    f32x4 acc[4][4];
#pragma unroll
    for (int ni = 0; ni < 4; ni++) {
        float bv_ = bp[n0 + wc * 64 + ni * 16 + fr];
#pragma unroll
        for (int mi = 0; mi < 4; mi++)
            acc[mi][ni] = (f32x4){bv_, bv_, bv_, bv_};
    }

    GEMM_KLOOP(yb, wp)

#pragma unroll
    for (int mi = 0; mi < 4; mi++)
#pragma unroll
        for (int ni = 0; ni < 4; ni++) {
            int n = n0 + wc * 64 + ni * 16 + fr;
#pragma unroll
            for (int r = 0; r < 4; r++) {
                int m = m0 + wr * 64 + mi * 16 + fg * 4 + r;
                out[(size_t)m * CC + n] = acc[mi][ni][r];
            }
        }
}

// ---------------------------------------------------------------------------
// Flash attention, software-pipelined (T15): two chunk-states in flight —
// softmax(S_cur) VALU overlaps QK-MFMA of S_next (separate pipes, m114).
// 3-buffer LDS rotation: iter ci reads V from buf ci%3, K(next) from (ci+1)%3,
// stages chunk ci+2 into (ci+2)%3 (gl_lds, drained by end-of-iter sync).
// K/V staged via global_load_lds with pre-swizzled SOURCE (rule #21):
// K slot s of row r holds chunk s^(r&7); V slot s^(r&3). Fixed-shift softmax
// p=exp2(S), shift in MFMA C-init; row-sum via ones-MFMA.
// Mask: valid iff (j%512) <= (i%512).
// ---------------------------------------------------------------------------
__global__ __launch_bounds__(128, 4) void attn(
    const unsigned short* __restrict__ q, const unsigned short* __restrict__ k,
    const unsigned short* __restrict__ vt, unsigned short* __restrict__ y) {
    __shared__ unsigned short Ks[3][32][64];
    __shared__ unsigned short Vs[3][64][32];
    __shared__ unsigned short Ps[2][16][40];

    const int gid = blockIdx.x;                 // 2304 = 8 slots x 6 bh x 48
    const int slot = gid & 7;
    const int rest = gid >> 3;                  // 0..287
    const int bh = slot * 6 + rest % 6;
    const int rank = rest / 6;                  // 0..47, heavy-first
    const int p32 = 15 - rank / 3;              // 32-row tile pos in segment
    const int sg0 = rank % 3;
    const int q0 = sg0 * 512 + p32 * 32;

    const int tid = threadIdx.x;
    const int w = tid >> 6;                     // 0..1
    const int lane = tid & 63;
    const int fr = lane & 15, fg = lane >> 4;

    const size_t base = (size_t)bh * TT * HD;
    const unsigned short* kk = k + base;
    const unsigned short* vv = vt + base;

    bf16x8 aq[2];
#pragma unroll
    for (int s = 0; s < 2; s++)
        aq[s] = *reinterpret_cast<const bf16x8*>(
            &q[base + (size_t)(q0 + w * 16 + fr) * HD + s * 32 + fg * 8]);

    f32x4 acc_o[4];
#pragma unroll
    for (int i = 0; i < 4; i++) acc_o[i] = (f32x4){0.f, 0.f, 0.f, 0.f};
    f32x4 acc_l = (f32x4){0.f, 0.f, 0.f, 0.f};

    const bf16x8 ones8 = {(short)0x3F80, (short)0x3F80, (short)0x3F80, (short)0x3F80,
                          (short)0x3F80, (short)0x3F80, (short)0x3F80, (short)0x3F80};
    const f32x4 sinit = {-SSHIFT, -SSHIFT, -SSHIFT, -SSHIFT};

    // gl_lds staging (R14-verified): per wave, 2 instrs K + 2 instrs V.
    auto stage = [&](int b, int k0n) {
#pragma unroll
        for (int i = 0; i < 2; i++) {
            const int rK = w * 16 + i * 8 + (lane >> 3);
            gl_lds16(&kk[(size_t)(k0n + rK) * HD + (((lane & 7) ^ (rK & 7)) * 8)],
                     &Ks[b][w * 16 + i * 8][0]);
            const int rV = w * 32 + i * 16 + (lane >> 2);
            gl_lds16(&vv[(size_t)rV * TT + k0n + (((lane & 3) ^ (rV & 3)) * 8)],
                     &Vs[b][w * 32 + i * 16][0]);
        }
    };

    // QK of one chunk from LDS buffer `b`, mask if diagonal (dg).
    auto qk = [&](int b, bool dg, f32x4* S) {
#pragma unroll
        for (int nb = 0; nb < 2; nb++) {
            f32x4 sa = sinit;         // shift folded into C-in
            const int krow = nb * 16 + fr;
#pragma unroll
            for (int s = 0; s < 2; s++) {
                bf16x8 bk_ = *reinterpret_cast<const bf16x8*>(
                    &Ks[b][krow][(((s * 4 + fg) ^ (krow & 7))) * 8]);
                sa = __builtin_amdgcn_mfma_f32_16x16x32_bf16(aq[s], bk_, sa, 0, 0, 0);
            }
            if (dg) {
#pragma unroll
                for (int r = 0; r < 4; r++) {
                    int ib = w * 16 + fg * 4 + r;      // q row within 32-tile
                    int jb = nb * 16 + fr;             // key within chunk
                    if (jb > ib) sa[r] = -1e30f;
                }
            }
            S[nb] = sa;
        }
    };

    const int per = p32 + 1;          // 32-key chunks per 512-segment
    const int ntot = 3 * per;

    // Prologue: stage chunks 0 and 1, drain, compute S(0).
    stage(0, 0);
    int ji = 0, si = 0;               // last-issued chunk coords
    if (ntot > 1) {
        ji++; if (ji == per) { ji = 0; si++; }
        stage(1, si * 512 + ji * 32);
    }
    __syncthreads();

    int jn = 0;                       // j of the chunk in S_cur
    f32x4 S_cur[2];
    qk(0, jn == per - 1, S_cur);

    int bC = 0, bN = 1, bW = 2;       // buffer roles: V-cur, K-next, write

    for (int ci = 0; ci < ntot; ci++) {
        if (ci + 2 < ntot) {          // prefetch chunk ci+2 (async into bW)
            ji++; if (ji == per) { ji = 0; si++; }
            stage(bW, si * 512 + ji * 32);
        }

        // softmax numerator of S_cur -> Ps (VALU; overlaps next QK MFMA)
#pragma unroll
        for (int nb = 0; nb < 2; nb++)
#pragma unroll
            for (int r = 0; r < 4; r++)
                Ps[w][fg * 4 + r][((nb ^ (fg >> 1)) * 16) + fr] =
                    nbf(exp2f(S_cur[nb][r]));

        // QK of chunk ci+1 (independent of softmax/PV of ci)
        f32x4 S_nxt[2];
        if (ci + 1 < ntot) {
            jn++; if (jn == per) jn = 0;
            qk(bN, jn == per - 1, S_nxt);
        }

        // PV of chunk ci
        bf16x8 ap = *reinterpret_cast<const bf16x8*>(
            &Ps[w][fr][(fg ^ (2 * (fr >> 3))) * 8]);
#pragma unroll
        for (int nd = 0; nd < 4; nd++) {
            const int vrow = nd * 16 + fr;
            bf16x8 bv_ = *reinterpret_cast<const bf16x8*>(
                &Vs[bC][vrow][((fg ^ (vrow & 3))) * 8]);
            acc_o[nd] = __builtin_amdgcn_mfma_f32_16x16x32_bf16(ap, bv_, acc_o[nd], 0, 0, 0);
        }
        acc_l = __builtin_amdgcn_mfma_f32_16x16x32_bf16(ap, ones8, acc_l, 0, 0, 0);

        __syncthreads();              // drains this iter's stage; rotate
        int t = bC; bC = bN; bN = bW; bW = t;
        S_cur[0] = S_nxt[0];
        S_cur[1] = S_nxt[1];
    }

    const int b_ = bh / NH, h = bh % NH;
#pragma unroll
    for (int r = 0; r < 4; r++) {
        float inv = 1.f / acc_l[r];
        int t = q0 + w * 16 + fg * 4 + r;
        size_t off = ((size_t)b_ * TT + t) * CC + h * HD;
#pragma unroll
        for (int nd = 0; nd < 4; nd++)
            y[off + nd * 16 + fr] = nbf(acc_o[nd][r] * inv);
    }
}

extern "C" void kernel_launch(void* const* d_in, const int* in_sizes, int n_in,
                              void* d_out, int out_size, void* d_ws, size_t ws_size,
                              hipStream_t stream) {
    const float* x  = (const float*)d_in[0];
    const float* Wq = (const float*)d_in[1];
    const float* bq = (const float*)d_in[2];
    const float* Wk = (const float*)d_in[3];
    const float* bk = (const float*)d_in[4];
    const float* Wv = (const float*)d_in[5];
    const float* bv = (const float*)d_in[6];
    const float* Wp = (const float*)d_in[7];
    const float* bp = (const float*)d_in[8];
    float* out = (float*)d_out;

    unsigned short* ws  = (unsigned short*)d_ws;
    unsigned short* wqb = ws;                              // CC*CC each
    unsigned short* wkb = wqb + (size_t)CC * CC;
    unsigned short* wvb = wkb + (size_t)CC * CC;
    unsigned short* wpb = wvb + (size_t)CC * CC;
    unsigned short* xb  = wpb + (size_t)CC * CC;           // MM*CC each
    unsigned short* qb_ = xb  + (size_t)MM * CC;
    unsigned short* kb_ = qb_ + (size_t)MM * CC;
    unsigned short* vt_ = kb_ + (size_t)MM * CC;           // [B,H,D,T]
    unsigned short* yb  = vt_ + (size_t)MM * CC;

    const int ntot4 = N4X + 4 * N4W;
    convert_all<<<(ntot4 + 255) / 256, 256, 0, stream>>>(
        x, Wq, Wk, Wv, Wp, xb, wqb, wkb, wvb, wpb);

    gemm_qkv<<<dim3(864), 256, 0, stream>>>(
        xb, wqb, bq, wkb, bk, wvb, bv, qb_, kb_, vt_);
    attn<<<dim3(2304), 128, 0, stream>>>(qb_, kb_, vt_, yb);
    gemm_proj<<<dim3(288), 256, 0, stream>>>(yb, wpb, bp, out);
}

// Round 16
// 97.708 us; speedup vs baseline: 1.2312x; 1.2312x over previous
//
#include <hip/hip_runtime.h>
#include <hip/hip_bf16.h>

typedef __attribute__((ext_vector_type(8))) short bf16x8;
typedef __attribute__((ext_vector_type(4))) float f32x4;

#define NH 12
#define HD 64
#define TT 1536
#define CC 768
#define BB 4
#define MM (BB * TT)   // 6144 rows
#define LOG2E 1.44269504088896f
#define SSHIFT 14.4269504089f   // 10*log2e

__device__ __forceinline__ unsigned short f2bf(float f) {
    unsigned int u = __builtin_bit_cast(unsigned int, f);
    return (unsigned short)((u + 0x7FFFu + ((u >> 16) & 1u)) >> 16);  // RNE
}

__device__ __forceinline__ unsigned short nbf(float f) {   // native convert
    __hip_bfloat16 h = __float2bfloat16(f);
    return __builtin_bit_cast(unsigned short, h);
}

// async global->LDS, 16B per lane; lds dest = wave-uniform base + lane*16
__device__ __forceinline__ void gl_lds16(const unsigned short* g, unsigned short* l) {
    __builtin_amdgcn_global_load_lds(
        (const __attribute__((address_space(1))) void*)g,
        (__attribute__((address_space(3))) void*)l,
        16, 0, 0);
}

// single launch: convert x and all 4 weights fp32 -> bf16 (region-decoded)
#define N4W (CC * CC / 4)
#define N4X (MM * CC / 4)
__global__ __launch_bounds__(256) void convert_all(
    const float* __restrict__ x,
    const float* __restrict__ w0, const float* __restrict__ w1,
    const float* __restrict__ w2, const float* __restrict__ w3,
    unsigned short* __restrict__ xo,
    unsigned short* __restrict__ o0, unsigned short* __restrict__ o1,
    unsigned short* __restrict__ o2, unsigned short* __restrict__ o3) {
    int i = blockIdx.x * 256 + threadIdx.x;
    const float* in;
    unsigned short* out;
    int j;
    if (i < N4X) {
        in = x; out = xo; j = i;
    } else {
        int t = i - N4X;
        int which = t / N4W;
        j = t - which * N4W;
        in = which == 0 ? w0 : which == 1 ? w1 : which == 2 ? w2 : w3;
        out = which == 0 ? o0 : which == 1 ? o1 : which == 2 ? o2 : o3;
    }
    float4 v = reinterpret_cast<const float4*>(in)[j];
    ushort4 o = { f2bf(v.x), f2bf(v.y), f2bf(v.z), f2bf(v.w) };
    reinterpret_cast<ushort4*>(out)[j] = o;
}

// Single-buffered K-loop (R11-proven), BK=64, 12 rounds, parametrized tile:
// A-tile = APASS*32 rows, per-wave M-frags = MI. Swizzle (rule #21): LDS slot
// s of row r holds global chunk s ^ (r&7); source pre-swizzled, read swizzled.
#define GEMM_KLOOP(APTR, BPTR, APASS, MI)                                     \
    for (int kt = 0; kt < 12; kt++) {                                         \
        const int k0 = kt * 64;                                               \
        __syncthreads();                                                      \
        _Pragma("unroll")                                                     \
        for (int i = 0; i < APASS; i++)                                       \
            gl_lds16(&APTR[(size_t)(m0 + i * 32 + sr) * CC + k0 + sc],        \
                     as0 + (i * 32 + w * 8) * 64);                            \
        _Pragma("unroll")                                                     \
        for (int i = 0; i < 4; i++)                                           \
            gl_lds16(&BPTR[(size_t)(n0 + i * 32 + sr) * CC + k0 + sc],        \
                     bs0 + (i * 32 + w * 8) * 64);                            \
        __syncthreads();                                                      \
        _Pragma("unroll")                                                     \
        for (int s = 0; s < 2; s++) {                                         \
            const int swz = ((s * 4 + fg) ^ (fr & 7)) * 8;                    \
            bf16x8 a[MI], b[4];                                               \
            _Pragma("unroll")                                                 \
            for (int mi = 0; mi < MI; mi++)                                   \
                a[mi] = *reinterpret_cast<const bf16x8*>(                     \
                    as0 + (wr * (MI * 16) + mi * 16 + fr) * 64 + swz);        \
            _Pragma("unroll")                                                 \
            for (int ni = 0; ni < 4; ni++)                                    \
                b[ni] = *reinterpret_cast<const bf16x8*>(                     \
                    bs0 + (wc * 64 + ni * 16 + fr) * 64 + swz);               \
            _Pragma("unroll")                                                 \
            for (int mi = 0; mi < MI; mi++)                                   \
                _Pragma("unroll")                                             \
                for (int ni = 0; ni < 4; ni++)                                \
                    acc[mi][ni] = __builtin_amdgcn_mfma_f32_16x16x32_bf16(    \
                        a[mi], b[ni], acc[mi][ni], 0, 0, 0);                  \
        }                                                                     \
    }

// ---------------------------------------------------------------------------
// QKV projection GEMM; 64x128 tile (1728 blocks = 6.75/CU, 24 KB LDS), BK=64
// swizzled gl_lds staging; bias folded into C-init. XCD swizzle 216/XCD.
// q -> [B,H,T,D] scaled 0.125*log2e; k -> [B,H,T,D]; v -> [B,H,D,T]
// ---------------------------------------------------------------------------
__global__ __launch_bounds__(256) void gemm_qkv(
    const unsigned short* __restrict__ xb,
    const unsigned short* __restrict__ wq, const float* __restrict__ bq,
    const unsigned short* __restrict__ wk, const float* __restrict__ bk,
    const unsigned short* __restrict__ wv, const float* __restrict__ bv,
    unsigned short* __restrict__ qo, unsigned short* __restrict__ ko,
    unsigned short* __restrict__ vo) {
    __shared__ unsigned short As[64][64];
    __shared__ unsigned short Bs[128][64];

    const int wg = (blockIdx.x & 7) * 216 + (blockIdx.x >> 3);  // nwg=1728
    const int z = wg / 576;
    const int rem = wg % 576;
    const int m0 = (rem / 6) * 64;
    const int n0 = (rem % 6) * 128;

    const unsigned short* W = (z == 0) ? wq : (z == 1) ? wk : wv;
    const float* bias = (z == 0) ? bq : (z == 1) ? bk : bv;
    unsigned short* out = (z == 0) ? qo : (z == 1) ? ko : vo;
    const float scale = (z == 0) ? 0.125f * LOG2E : 1.0f;

    const int tid = threadIdx.x;
    const int lane = tid & 63;
    const int w = tid >> 6;
    const int wr = w >> 1, wc = w & 1;
    const int fr = lane & 15, fg = lane >> 4;

    const int sr = tid >> 3;
    const int sc = ((tid & 7) ^ ((tid >> 3) & 7)) * 8;
    unsigned short* as0 = &As[0][0];
    unsigned short* bs0 = &Bs[0][0];

    f32x4 acc[2][4];
#pragma unroll
    for (int ni = 0; ni < 4; ni++) {
        float bv_ = bias[n0 + wc * 64 + ni * 16 + fr];
#pragma unroll
        for (int mi = 0; mi < 2; mi++)
            acc[mi][ni] = (f32x4){bv_, bv_, bv_, bv_};
    }

    GEMM_KLOOP(xb, W, 2, 2)

#pragma unroll
    for (int mi = 0; mi < 2; mi++)
#pragma unroll
        for (int ni = 0; ni < 4; ni++) {
            int n = n0 + wc * 64 + ni * 16 + fr;
            int h = n >> 6, d = n & 63;
            int m_base = m0 + wr * 32 + mi * 16 + fg * 4;
            int b_ = m_base / TT, t0 = m_base % TT;
            if (z == 2) {
                size_t off = ((size_t)(b_ * NH + h) * HD + d) * (size_t)TT + t0;
                ushort4 o = { nbf(acc[mi][ni][0]), nbf(acc[mi][ni][1]),
                              nbf(acc[mi][ni][2]), nbf(acc[mi][ni][3]) };
                *reinterpret_cast<ushort4*>(&out[off]) = o;
            } else {
#pragma unroll
                for (int r = 0; r < 4; r++) {
                    size_t off = ((size_t)(b_ * NH + h) * TT + t0 + r) * (size_t)HD + d;
                    out[off] = nbf(acc[mi][ni][r] * scale);
                }
            }
        }
}

// ---------------------------------------------------------------------------
// Output projection GEMM: 64x128 tile (576 blocks), same staging; bias in
// C-init. fp32 out [M,C]. XCD swizzle 72/XCD.
// ---------------------------------------------------------------------------
__global__ __launch_bounds__(256) void gemm_proj(
    const unsigned short* __restrict__ yb,
    const unsigned short* __restrict__ wp, const float* __restrict__ bp,
    float* __restrict__ out) {
    __shared__ unsigned short As[64][64];
    __shared__ unsigned short Bs[128][64];

    const int wg = (blockIdx.x & 7) * 72 + (blockIdx.x >> 3);  // nwg=576
    const int m0 = (wg / 6) * 64;
    const int n0 = (wg % 6) * 128;

    const int tid = threadIdx.x;
    const int lane = tid & 63;
    const int w = tid >> 6;
    const int wr = w >> 1, wc = w & 1;
    const int fr = lane & 15, fg = lane >> 4;

    const int sr = tid >> 3;
    const int sc = ((tid & 7) ^ ((tid >> 3) & 7)) * 8;
    unsigned short* as0 = &As[0][0];
    unsigned short* bs0 = &Bs[0][0];

    f32x4 acc[2][4];
#pragma unroll
    for (int ni = 0; ni < 4; ni++) {
        float bv_ = bp[n0 + wc * 64 + ni * 16 + fr];
#pragma unroll
        for (int mi = 0; mi < 2; mi++)
            acc[mi][ni] = (f32x4){bv_, bv_, bv_, bv_};
    }

    GEMM_KLOOP(yb, wp, 2, 2)

#pragma unroll
    for (int mi = 0; mi < 2; mi++)
#pragma unroll
        for (int ni = 0; ni < 4; ni++) {
            int n = n0 + wc * 64 + ni * 16 + fr;
#pragma unroll
            for (int r = 0; r < 4; r++) {
                int m = m0 + wr * 32 + mi * 16 + fg * 4 + r;
                out[(size_t)m * CC + n] = acc[mi][ni][r];
            }
        }
}

// ---------------------------------------------------------------------------
// Flash attention (R12-proven, 48.2 us — reverted verbatim): fixed-shift
// softmax p=exp2(S) with shift in MFMA C-init; row-sum via ones-MFMA;
// KCHUNK=32, double-buffered K/V^T LDS (register-staged), 1 barrier/chunk;
// XCD-clustered bh; heavy-first q-tiles. Mask: valid iff (j%512) <= (i%512).
// ---------------------------------------------------------------------------
__global__ __launch_bounds__(256) void attn(
    const unsigned short* __restrict__ q, const unsigned short* __restrict__ k,
    const unsigned short* __restrict__ vt, unsigned short* __restrict__ y) {
    __shared__ unsigned short Ks[2][32][72];
    __shared__ unsigned short Vs[2][64][40];
    __shared__ unsigned short Ps[4][16][40];

    const int gid = blockIdx.x;
    const int slot = gid & 7;
    const int sub = (gid >> 3) % 6;
    const int bh = slot * 6 + sub;              // 6 bh per XCD slot
    const int qt = gid / 48;                    // 0..23, heavy-first
    const int qseg = 7 - qt / 3;                // 7..0
    const int sg0 = qt % 3;
    const int q0 = sg0 * 512 + qseg * 64;

    const int tid = threadIdx.x;
    const int w = tid >> 6;
    const int lane = tid & 63;
    const int fr = lane & 15, fg = lane >> 4;

    const size_t base = (size_t)bh * TT * HD;

    bf16x8 aq[2];
#pragma unroll
    for (int s = 0; s < 2; s++)
        aq[s] = *reinterpret_cast<const bf16x8*>(
            &q[base + (size_t)(q0 + w * 16 + fr) * HD + s * 32 + fg * 8]);

    f32x4 acc_o[4];
#pragma unroll
    for (int i = 0; i < 4; i++) acc_o[i] = (f32x4){0.f, 0.f, 0.f, 0.f};
    f32x4 acc_l = (f32x4){0.f, 0.f, 0.f, 0.f};

    const bf16x8 ones8 = {(short)0x3F80, (short)0x3F80, (short)0x3F80, (short)0x3F80,
                          (short)0x3F80, (short)0x3F80, (short)0x3F80, (short)0x3F80};
    const f32x4 sinit = {-SSHIFT, -SSHIFT, -SSHIFT, -SSHIFT};

    const int kr = tid >> 3, kc = tid & 7;
    const int vr = tid >> 2, vc = tid & 3;

    uint4 kreg, vreg;
    auto issue = [&](int k0n) {
        kreg = *reinterpret_cast<const uint4*>(&k[base + (size_t)(k0n + kr) * HD + kc * 8]);
        vreg = *reinterpret_cast<const uint4*>(&vt[base + (size_t)vr * TT + k0n + vc * 8]);
    };
    auto wlds = [&](int b) {
        *reinterpret_cast<uint4*>(&Ks[b][kr][kc * 8]) = kreg;
        *reinterpret_cast<uint4*>(&Vs[b][vr][vc * 8]) = vreg;
    };

    const int per = 2 * qseg + 2;     // 32-key chunks per 512-segment
    const int ntot = 3 * per;

    issue(0);
    wlds(0);
    int cur = 0;
    int j = 0;
    int ji = 0, si = 0;

    for (int ci = 0; ci < ntot; ci++) {
        if (ci + 1 < ntot) {
            ji++; if (ji == per) { ji = 0; si++; }
            issue(si * 512 + ji * 32);
        }
        __syncthreads();

        f32x4 S[2];
#pragma unroll
        for (int nb = 0; nb < 2; nb++) {
            f32x4 sa = sinit;         // shift folded into C-in
#pragma unroll
            for (int s = 0; s < 2; s++) {
                bf16x8 bk_ = *reinterpret_cast<const bf16x8*>(
                    &Ks[cur][nb * 16 + fr][s * 32 + fg * 8]);
                sa = __builtin_amdgcn_mfma_f32_16x16x32_bf16(aq[s], bk_, sa, 0, 0, 0);
            }
            S[nb] = sa;
        }

        if (j >= 2 * qseg) {
            const int joff = (j - 2 * qseg) * 32;
#pragma unroll
            for (int nb = 0; nb < 2; nb++)
#pragma unroll
                for (int r = 0; r < 4; r++) {
                    int ib = w * 16 + fg * 4 + r;
                    int jb = joff + nb * 16 + fr;
                    if (jb > ib) S[nb][r] = -1e30f;
                }
        }

        // p = 2^S (already shifted); native bf16 convert; swizzled Ps
#pragma unroll
        for (int nb = 0; nb < 2; nb++)
#pragma unroll
            for (int r = 0; r < 4; r++)
                Ps[w][fg * 4 + r][((nb ^ (fg >> 1)) * 16) + fr] =
                    nbf(exp2f(S[nb][r]));

        bf16x8 ap = *reinterpret_cast<const bf16x8*>(
            &Ps[w][fr][(fg ^ (2 * (fr >> 3))) * 8]);
#pragma unroll
        for (int nd = 0; nd < 4; nd++) {
            bf16x8 bv_ = *reinterpret_cast<const bf16x8*>(&Vs[cur][nd * 16 + fr][fg * 8]);
            acc_o[nd] = __builtin_amdgcn_mfma_f32_16x16x32_bf16(ap, bv_, acc_o[nd], 0, 0, 0);
        }
        acc_l = __builtin_amdgcn_mfma_f32_16x16x32_bf16(ap, ones8, acc_l, 0, 0, 0);

        if (ci + 1 < ntot) wlds(cur ^ 1);
        cur ^= 1;
        if (++j == per) j = 0;
    }

    const int b_ = bh / NH, h = bh % NH;
#pragma unroll
    for (int r = 0; r < 4; r++) {
        float inv = 1.f / acc_l[r];
        int t = q0 + w * 16 + fg * 4 + r;
        size_t off = ((size_t)b_ * TT + t) * CC + h * HD;
#pragma unroll
        for (int nd = 0; nd < 4; nd++)
            y[off + nd * 16 + fr] = nbf(acc_o[nd][r] * inv);
    }
}

extern "C" void kernel_launch(void* const* d_in, const int* in_sizes, int n_in,
                              void* d_out, int out_size, void* d_ws, size_t ws_size,
                              hipStream_t stream) {
    const float* x  = (const float*)d_in[0];
    const float* Wq = (const float*)d_in[1];
    const float* bq = (const float*)d_in[2];
    const float* Wk = (const float*)d_in[3];
    const float* bk = (const float*)d_in[4];
    const float* Wv = (const float*)d_in[5];
    const float* bv = (const float*)d_in[6];
    const float* Wp = (const float*)d_in[7];
    const float* bp = (const float*)d_in[8];
    float* out = (float*)d_out;

    unsigned short* ws  = (unsigned short*)d_ws;
    unsigned short* wqb = ws;                              // CC*CC each
    unsigned short* wkb = wqb + (size_t)CC * CC;
    unsigned short* wvb = wkb + (size_t)CC * CC;
    unsigned short* wpb = wvb + (size_t)CC * CC;
    unsigned short* xb  = wpb + (size_t)CC * CC;           // MM*CC each
    unsigned short* qb_ = xb  + (size_t)MM * CC;
    unsigned short* kb_ = qb_ + (size_t)MM * CC;
    unsigned short* vt_ = kb_ + (size_t)MM * CC;           // [B,H,D,T]
    unsigned short* yb  = vt_ + (size_t)MM * CC;

    const int ntot4 = N4X + 4 * N4W;
    convert_all<<<(ntot4 + 255) / 256, 256, 0, stream>>>(
        x, Wq, Wk, Wv, Wp, xb, wqb, wkb, wvb, wpb);

    gemm_qkv<<<dim3(1728), 256, 0, stream>>>(
        xb, wqb, bq, wkb, bk, wvb, bv, qb_, kb_, vt_);
    attn<<<dim3(48 * 24), 256, 0, stream>>>(qb_, kb_, vt_, yb);
    gemm_proj<<<dim3(576), 256, 0, stream>>>(yb, wpb, bp, out);
}